// Round 6
// baseline (100.684 us; speedup 1.0000x reference)
//
#include <hip/hip_runtime.h>
#include <hip/hip_bf16.h>

// out[b, 2t+r, c*128+d] = normed outer product of x[b,t,:] with itself.
// ||flatten(w*x⊗x)||_2 = |w| * (Σ x_c^2)  => per-frame: 128-elem sum of squares
// + rank-1 outer product streamed twice (UpSampling1D repeat).
// Pure HBM-write-bound: 512 MiB writes, 2 MiB reads.
//
// Round 6: FPB=4 (best), single strictly-ascending store stream over the
// combined 2-row (128 KiB) frame region instead of two interleaved streams
// 64 KiB apart — final A/B vs the fill kernel's access pattern.

#define C 128
#define CC (C * C)        // 16384
#define CC4 (CC / 4)      // 4096 float4 per time-row
#define FRAME4 (2 * CC4)  // 8192 float4 per frame region (both repeated rows)
#define NTHREADS 256
#define FPB 4             // frames per block
#define EPS 1e-12f

typedef float f32x4 __attribute__((ext_vector_type(4)));

__global__ __launch_bounds__(NTHREADS) void frame_outer_kernel(
    const float* __restrict__ x,   // (BT, 128)
    const float* __restrict__ w,   // (1,)
    float* __restrict__ out)       // (BT*2, 16384)
{
    __shared__ __align__(16) float xs[FPB][C];
    __shared__ float par[8];   // par[4*j + wid], load j covers rows 2j,2j+1

    const int tid = threadIdx.x;
    const int wid = tid >> 6;
    const int frame0 = blockIdx.x * FPB;
    const float* __restrict__ xr = x + (size_t)frame0 * C;

    // Load 4 rows (512 floats): 2 elements per thread.
    const float v0 = xr[tid];          // rows 0-1
    const float v1 = xr[tid + 256];    // rows 2-3
    ((float*)xs)[tid]       = v0;
    ((float*)xs)[tid + 256] = v1;

    float p0 = v0 * v0;
    float p1 = v1 * v1;
    #pragma unroll
    for (int off = 32; off > 0; off >>= 1) {
        p0 += __shfl_down(p0, off);
        p1 += __shfl_down(p1, off);
    }
    if ((tid & 63) == 0) {
        par[wid]     = p0;
        par[wid + 4] = p1;
    }
    __syncthreads();   // xs[] and par[] ready

    const float wv = w[0];
    float wrs[FPB];
    #pragma unroll
    for (int fi = 0; fi < FPB; ++fi) {
        const float S = par[2 * fi] + par[2 * fi + 1];
        const float ws = wv * S;
        wrs[fi] = wv * rsqrtf(fmaxf(ws * ws, EPS));
    }

    // Stream stores, strictly ascending addresses: the two repeated time-rows
    // form one contiguous 8192-float4 region; value depends only on i mod 4096.
    const int d4 = tid & 31;   // float4 column — fixed per thread
    #pragma unroll
    for (int fi = 0; fi < FPB; ++fi) {
        const f32x4 xv = ((const f32x4*)xs[fi])[d4];
        const float a0 = wrs[fi];
        f32x4* __restrict__ o = (f32x4*)(out + (size_t)(frame0 + fi) * 2 * CC);
        #pragma unroll
        for (int k = 0; k < FRAME4 / NTHREADS; ++k) {   // 32 iterations
            const int i = k * NTHREADS + tid;           // 0..8191, ascending
            const int c = (i >> 5) & (C - 1);           // outer-product row (broadcast read)
            const float a = a0 * xs[fi][c];
            o[i] = a * xv;
        }
    }
}

extern "C" void kernel_launch(void* const* d_in, const int* in_sizes, int n_in,
                              void* d_out, int out_size, void* d_ws, size_t ws_size,
                              hipStream_t stream) {
    const float* x = (const float*)d_in[0];
    const float* w = (const float*)d_in[1];
    float* out = (float*)d_out;

    const int BT = in_sizes[0] / C;          // 4096 frames
    const int nblocks = BT / FPB;            // 1024 blocks = 4 per CU
    frame_outer_kernel<<<nblocks, NTHREADS, 0, stream>>>(x, w, out);
}

// Round 7
// 90.028 us; speedup vs baseline: 1.1184x; 1.1184x over previous
//
#include <hip/hip_runtime.h>
#include <hip/hip_bf16.h>

// out[b, 2t+r, c*128+d] = normed outer product of x[b,t,:] with itself.
// ||flatten(w*x⊗x)||_2 = |w| * (Σ x_c^2)  => per-frame: 128-elem sum of squares
// + rank-1 outer product streamed twice (UpSampling1D repeat).
// Pure HBM-write-bound: 512 MiB writes, 2 MiB reads.
//
// Round 7: revert to R4 structure (FPB=4, dual-stream stores: one LDS read
// feeds two stores — mono-stream R6 cost 10%). Final A/B: nontemporal flag
// on the FPB=4 structure.

#define C 128
#define CC (C * C)       // 16384
#define CC4 (CC / 4)     // 4096 float4 per time-row
#define NTHREADS 256
#define FPB 4            // frames per block
#define EPS 1e-12f

typedef float f32x4 __attribute__((ext_vector_type(4)));

__global__ __launch_bounds__(NTHREADS) void frame_outer_kernel(
    const float* __restrict__ x,   // (BT, 128)
    const float* __restrict__ w,   // (1,)
    float* __restrict__ out)       // (BT*2, 16384)
{
    __shared__ __align__(16) float xs[FPB][C];
    __shared__ float par[8];   // per-wave partials: [0..3] rows 0-1, [4..7] rows 2-3

    const int tid = threadIdx.x;
    const int wid = tid >> 6;
    const int frame0 = blockIdx.x * FPB;
    const float* __restrict__ xr = x + (size_t)frame0 * C;

    // Load 4 rows (512 floats) with 256 threads, 2 elements each.
    const float v0 = xr[tid];          // rows 0-1
    const float v1 = xr[tid + 256];    // rows 2-3
    ((float*)xs)[tid]       = v0;
    ((float*)xs)[tid + 256] = v1;

    float p0 = v0 * v0;
    float p1 = v1 * v1;
    #pragma unroll
    for (int off = 32; off > 0; off >>= 1) {
        p0 += __shfl_down(p0, off);
        p1 += __shfl_down(p1, off);
    }
    if ((tid & 63) == 0) {
        par[wid]     = p0;
        par[wid + 4] = p1;
    }
    __syncthreads();   // xs[] and par[] ready

    const float wv = w[0];
    float wrs[FPB];
    #pragma unroll
    for (int fi = 0; fi < FPB; ++fi) {
        const float S = par[2 * fi] + par[2 * fi + 1];
        const float ws = wv * S;
        wrs[fi] = wv * rsqrtf(fmaxf(ws * ws, EPS));
    }

    // Stream stores: for each frame, out[c*128+d] = (wrs*xs[c]) * xs[d],
    // written to time rows 2t and 2t+1. One LDS read feeds two stores.
    const int d4 = tid & 31;   // float4 column — fixed per thread
    #pragma unroll
    for (int fi = 0; fi < FPB; ++fi) {
        const f32x4 xv = ((const f32x4*)xs[fi])[d4];
        const float a0 = wrs[fi];
        float* __restrict__ obase = out + (size_t)(frame0 + fi) * 2 * CC;
        f32x4* __restrict__ o0 = (f32x4*)obase;
        f32x4* __restrict__ o1 = (f32x4*)(obase + CC);
        #pragma unroll
        for (int k = 0; k < CC4 / NTHREADS; ++k) {   // 16 iterations
            const int i = k * NTHREADS + tid;
            const int c = i >> 5;                    // broadcast LDS read (2 addrs/wave)
            const float a = a0 * xs[fi][c];
            f32x4 r = a * xv;
            __builtin_nontemporal_store(r, o0 + i);
            __builtin_nontemporal_store(r, o1 + i);
        }
    }
}

extern "C" void kernel_launch(void* const* d_in, const int* in_sizes, int n_in,
                              void* d_out, int out_size, void* d_ws, size_t ws_size,
                              hipStream_t stream) {
    const float* x = (const float*)d_in[0];
    const float* w = (const float*)d_in[1];
    float* out = (float*)d_out;

    const int BT = in_sizes[0] / C;          // 4096 frames
    const int nblocks = BT / FPB;            // 1024 blocks = 4 per CU
    frame_outer_kernel<<<nblocks, NTHREADS, 0, stream>>>(x, w, out);
}